// Round 6
// baseline (24.559 us; speedup 1.0000x reference)
//
#include <hip/hip_runtime.h>

// TreeLoss: 2-level hierarchical softmax loss.
// z(b)    = 1 + sum_p e^{x_p} * (1 + sum_{c in p} e^{x_c})   (parents p=56..63)
// loss(b) = log z - (x_g + x_parent(g)),  parent(g) = 56 + g/7; out = mean.
//
// R6: NO LDS data staging (R5 post-mortem: ~66 scalar LDS ops/row = 5.3us of
// serialized LDS-pipe per CU was the limiter; input is L3-resident so the
// memory floor is far below that). One full row per thread via 16x
// global_load_dwordx4 (lines MSHR-merge; L2 traffic stays 64MB). Child exps
// accumulate into 8 statically-indexed parent sums (no runtime-indexed
// arrays -> no scratch). Marginal term re-loads x_g / x_parent as scalars
// (L1-hot: this thread just fetched that line) instead of register-indexing.

#define RPB     256
#define THREADS 256

__device__ __forceinline__ float elem(const float4& v, int j) {
    return j == 0 ? v.x : j == 1 ? v.y : j == 2 ? v.z : v.w;
}

__global__ void __launch_bounds__(THREADS) tree_loss_partial(
    const float* __restrict__ pred,   // [rows, 64]
    const int*   __restrict__ gt,     // [rows] 0..55
    float*       __restrict__ partial,// [gridDim.x]
    int rows)
{
    __shared__ float wsum[THREADS / 64];

    const int t   = threadIdx.x;
    const int row = blockIdx.x * RPB + t;

    float loss = 0.0f;
    if (row < rows) {
        const float4* p4 = (const float4*)(pred + (size_t)row * 64);

        float4 v[16];
        #pragma unroll
        for (int i = 0; i < 16; ++i) v[i] = p4[i];   // 16 loads in flight

        // Child-exp sums per parent; all indices compile-time constant.
        float S[8];
        #pragma unroll
        for (int p = 0; p < 8; ++p) S[p] = 0.0f;
        #pragma unroll
        for (int i = 0; i < 14; ++i) {               // chunks 0..13 = cols 0..55
            #pragma unroll
            for (int j = 0; j < 4; ++j) {
                constexpr int dummy = 0; (void)dummy;
                const int col = 4 * i + j;           // compile-time after unroll
                S[col / 7] += __expf(elem(v[i], j));
            }
        }
        float z = 1.0f;
        #pragma unroll
        for (int p = 0; p < 8; ++p) {
            const int i = (56 + p) >> 2, j = (56 + p) & 3;  // chunks 14,15
            z += __expf(elem(v[i], j)) * (1.0f + S[p]);
        }

        int g = gt[row];                              // coalesced
        // x_g, x_parent: 2 scalar re-loads from this row (L1-resident line).
        float xg = pred[(size_t)row * 64 + g];
        float xp = pred[(size_t)row * 64 + 56 + g / 7];
        loss = __logf(z) - xg - xp;
    }

    // Block reduction.
    #pragma unroll
    for (int off = 32; off; off >>= 1) loss += __shfl_xor(loss, off);
    if ((t & 63) == 0) wsum[t >> 6] = loss;
    __syncthreads();
    if (t == 0) {
        float b = 0.0f;
        #pragma unroll
        for (int w = 0; w < THREADS / 64; ++w) b += wsum[w];
        partial[blockIdx.x] = b;
    }
}

__global__ void __launch_bounds__(256) tree_loss_final(
    const float* __restrict__ partial, int n,
    float* __restrict__ out, float inv)
{
    float s = 0.0f;
    for (int i = threadIdx.x; i < n; i += 256) s += partial[i];
    #pragma unroll
    for (int off = 32; off; off >>= 1) s += __shfl_xor(s, off);
    __shared__ float w[4];
    const int lane = threadIdx.x & 63;
    const int wv   = threadIdx.x >> 6;
    if (lane == 0) w[wv] = s;
    __syncthreads();
    if (threadIdx.x == 0) out[0] = (w[0] + w[1] + w[2] + w[3]) * inv;
}

extern "C" void kernel_launch(void* const* d_in, const int* in_sizes, int n_in,
                              void* d_out, int out_size, void* d_ws, size_t ws_size,
                              hipStream_t stream) {
    const float* pred = (const float*)d_in[0];   // [B,64] fp32
    const int*   gt   = (const int*)d_in[1];     // [B] int32
    float* out     = (float*)d_out;
    float* partial = (float*)d_ws;
    const int rows = in_sizes[1];                // BATCH = 262144

    const int blocks = (rows + RPB - 1) / RPB;   // 1024
    tree_loss_partial<<<blocks, THREADS, 0, stream>>>(pred, gt, partial, rows);
    tree_loss_final<<<1, 256, 0, stream>>>(partial, blocks, out, 1.0f / (float)rows);
}

// Round 7
// 21.654 us; speedup vs baseline: 1.1341x; 1.1341x over previous
//
#include <hip/hip_runtime.h>

// TreeLoss: 2-level hierarchical softmax loss.
// z(b)    = 1 + sum_p e^{x_p} * (1 + sum_{c in p} e^{x_c})   (parents p=56..63)
// loss(b) = log(z / (e^{x_g} * e^{x_parent(g)})),  parent(g) = 56 + g/7.
//
// R7: BARRIER-FREE wave-private staging. R3/R5 post-mortem: block-wide
// __syncthreads convoys all waves through stage->compute phases together, so
// VMEM idles during compute (~17us = 10.6us mem + ~6us unoverlapped LDS/VALU).
// Here each wave stages 32 rows exp'd into its OWN LDS region and consumes
// them itself -- intra-wave ds hazards are handled by compiler lgkmcnt waits,
// no barrier, so waves desync and memory/LDS/VALU phases overlap across the
// 16 resident waves/CU. Stride 65 keeps exact 2-lanes/bank (free) on both
// the write and read phases.

#define THREADS 256               // 4 waves
#define WROWS   32                // rows per wave
#define RPB     (4 * WROWS)       // 128 rows per block
#define STRIDE  65

__global__ void __launch_bounds__(THREADS) tree_loss_partial(
    const float* __restrict__ pred,   // [rows, 64]
    const int*   __restrict__ gt,     // [rows] 0..55
    float*       __restrict__ partial,// [gridDim.x]
    int rows)
{
    __shared__ float lds[4 * WROWS * STRIDE];   // 33280 B -> 4 blocks/CU
    __shared__ float wsum[4];

    const int t = threadIdx.x;
    const int w = t >> 6;
    const int l = t & 63;
    const int waveRowBase = blockIdx.x * RPB + w * WROWS;
    float* e_base = &lds[w * WROWS * STRIDE];

    // ---- Stage (wave-private): 32 rows = 512 float4 / 64 lanes = 8 each.
    // Issue all 8 loads first (in flight together), then exp+write.
    const float4* p4 = (const float4*)pred + (size_t)waveRowBase * 16;
    const bool full = (waveRowBase + WROWS <= rows);
    float4 v[8];
    #pragma unroll
    for (int i = 0; i < 8; ++i) {
        const int f = i * 64 + l;
        v[i] = (full || waveRowBase + (f >> 4) < rows)
                 ? p4[f] : make_float4(0.f, 0.f, 0.f, 0.f);
    }
    #pragma unroll
    for (int i = 0; i < 8; ++i) {
        const int f   = i * 64 + l;
        const int row = f >> 4;
        const int c4  = (f & 15) << 2;
        float* dst = e_base + row * STRIDE + c4;   // bank (row+col)%32: 2/bank
        dst[0] = __expf(v[i].x); dst[1] = __expf(v[i].y);
        dst[2] = __expf(v[i].z); dst[3] = __expf(v[i].w);
    }
    // NO __syncthreads: this wave wrote, this wave reads (lgkmcnt only).

    // ---- Compute: 2 lanes per row (hi = parents 0-3 / 4-7 halves).
    const int r  = l & 31;
    const int hi = l >> 5;
    const float* e  = e_base + r * STRIDE;
    const float* ec = e + hi * 28;
    const float* ep = e + 56 + hi * 4;
    float zh = 0.f;
    #pragma unroll
    for (int p = 0; p < 4; ++p) {
        float s = 1.f;
        #pragma unroll
        for (int c = 0; c < 7; ++c) s += ec[p * 7 + c];
        zh += ep[p] * s;
    }
    const float zo = __shfl_xor(zh, 32);       // other half's partial z

    const int rowg = waveRowBase + r;
    const bool valid = (rowg < rows);
    const int g = valid ? gt[rowg] : 0;        // coalesced (lanes 0..31 = rows)
    const float z = 1.f + zh + zo;
    const float m = e[g] * e[56 + g / 7];      // 2 ds gathers, L1... LDS-hot
    float loss = __logf(z / m);
    loss = (hi == 0 && valid) ? loss : 0.f;    // count each row once

    // ---- Wave + block reduction.
    #pragma unroll
    for (int off = 32; off; off >>= 1) loss += __shfl_xor(loss, off);
    if (l == 0) wsum[w] = loss;
    __syncthreads();                            // cold path, once per block
    if (t == 0) partial[blockIdx.x] = wsum[0] + wsum[1] + wsum[2] + wsum[3];
}

__global__ void __launch_bounds__(256) tree_loss_final(
    const float* __restrict__ partial, int n,
    float* __restrict__ out, float inv)
{
    float s = 0.0f;
    for (int i = threadIdx.x; i < n; i += 256) s += partial[i];
    #pragma unroll
    for (int off = 32; off; off >>= 1) s += __shfl_xor(s, off);
    __shared__ float w[4];
    const int lane = threadIdx.x & 63;
    const int wv   = threadIdx.x >> 6;
    if (lane == 0) w[wv] = s;
    __syncthreads();
    if (threadIdx.x == 0) out[0] = (w[0] + w[1] + w[2] + w[3]) * inv;
}

extern "C" void kernel_launch(void* const* d_in, const int* in_sizes, int n_in,
                              void* d_out, int out_size, void* d_ws, size_t ws_size,
                              hipStream_t stream) {
    const float* pred = (const float*)d_in[0];   // [B,64] fp32
    const int*   gt   = (const int*)d_in[1];     // [B] int32
    float* out     = (float*)d_out;
    float* partial = (float*)d_ws;
    const int rows = in_sizes[1];                // BATCH = 262144

    const int blocks = (rows + RPB - 1) / RPB;   // 2048
    tree_loss_partial<<<blocks, THREADS, 0, stream>>>(pred, gt, partial, rows);
    tree_loss_final<<<1, 256, 0, stream>>>(partial, blocks, out, 1.0f / (float)rows);
}